// Round 13
// baseline (440.130 us; speedup 1.0000x reference)
//
#include <hip/hip_runtime.h>

// QuantizedLinear: out[b,s,o] = sum_k x[b,s,k] * qw[o,k]
// qw = Wint/(9*alpha), Wint in {-2..2}  -> INT8 MFMA GEMM:
//   x quantized per-row to i8 (s_m = rowmax/127), W exact in i8,
//   i32 accumulation exact; epilogue scales by s_m/(9*alpha).
// M=16384, N=4096, K=4096. fp32 in/out.
//
// R13: small-block occupancy port. All 512-thr variants pinned at 8
//   waves/CU (register pool: 156 regs/wave x 16 waves > 2048 -- R9 retro),
//   so SIMD-mates stay phase-locked and LDS+MFMA time SUMS (2700 cyc/tile).
//   m97 mechanism needs >=3 independent blocks/CU: here 256-thr blocks,
//   128x128 tile, 64x64 wave-tile -> acc 64 AGPR + ~small VGPR -> 12
//   waves/CU; LDS quad-A + double-B = 48 KiB -> 3 blocks/CU. Cross-block
//   anti-phasing covers lgkm/vmcnt/barrier waits -> max() not sum().
// Kept: conflict-free (r>>1)&3 image swizzle (0 conflicts, re-derived for
//   128-row tiles), 2 phases/tile with lgkm0+SBAR gates (R6 spill lesson),
//   positional staging + vmcnt(2) ledger, static quad-A rotation (4x
//   unroll, compile-time LDS addrs), XCD-chunked swizzle, fused prepass.

typedef unsigned short u16;
typedef unsigned int u32;
typedef signed char s8;
typedef int v4i __attribute__((ext_vector_type(4)));

#define MDIM 16384
#define NDIM 4096
#define KDIM 4096

// ---------- helpers ----------

__device__ __forceinline__ float quant_wint(float w, float alpha) {
  // nearest of {3.5,4.0,4.5,5.0,5.5} to 4.5*(1+w*alpha); argmin tie -> lower level.
  float tv = 4.5f * (1.0f + w * alpha);
  float u = (tv - 3.5f) * 2.0f;
  float f = ceilf(u - 0.5f);
  f = fminf(fmaxf(f, 0.0f), 4.0f);
  return f - 2.0f;                  // Wint in {-2..2}; scale 1/(9*alpha) in epilogue
}

__device__ __forceinline__ void gld16(const void* g, void* l) {
  __builtin_amdgcn_global_load_lds(
      (const __attribute__((address_space(1))) void*)g,
      (__attribute__((address_space(3))) void*)l, 16, 0, 0);
}

__device__ __forceinline__ int q8(float x, float sinv) {
  float f = rintf(x * sinv);
  f = fminf(fmaxf(f, -127.0f), 127.0f);
  return (int)f;
}

// ---------- fused prepass: X rows then W rows, chunked+swizzled images ----------
// chunk(rowblk256,kblk64) = 16384B; image[r*64 + (c ^ (((r>>1)&3)<<4))]

__global__ __launch_bounds__(256) void quant_xw_kernel(
    const float4* __restrict__ X, const float4* __restrict__ W,
    const float* __restrict__ pAlpha,
    s8* __restrict__ Xq, s8* __restrict__ Wq, float* __restrict__ scales) {
  const int b = blockIdx.x;
  const int t = threadIdx.x;
  if (b < MDIM) {
    // ---- x row: per-row absmax scale -> i8 ----
    const int m = b;
    const float4* row = X + (size_t)m * 1024;
    float4 v0 = row[t * 4 + 0], v1 = row[t * 4 + 1], v2 = row[t * 4 + 2], v3 = row[t * 4 + 3];
    float vals[16] = {v0.x, v0.y, v0.z, v0.w, v1.x, v1.y, v1.z, v1.w,
                      v2.x, v2.y, v2.z, v2.w, v3.x, v3.y, v3.z, v3.w};
    float mx = 0.0f;
#pragma unroll
    for (int j = 0; j < 16; ++j) mx = fmaxf(mx, fabsf(vals[j]));
#pragma unroll
    for (int s = 1; s < 64; s <<= 1) mx = fmaxf(mx, __shfl_xor(mx, s));
    __shared__ float red[4];
    if ((t & 63) == 0) red[t >> 6] = mx;
    __syncthreads();
    float rmax = fmaxf(fmaxf(red[0], red[1]), fmaxf(red[2], red[3]));
    float sinv = rmax > 0.0f ? 127.0f / rmax : 0.0f;
    if (t == 0) scales[m] = rmax * (1.0f / 127.0f);
    u32 pk[4];
#pragma unroll
    for (int p = 0; p < 4; ++p) {
      u32 w = 0;
#pragma unroll
      for (int j = 0; j < 4; ++j)
        w |= ((u32)(unsigned char)(signed char)q8(vals[p * 4 + j], sinv)) << (8 * j);
      pk[p] = w;
    }
    size_t chunk = ((size_t)(m >> 8) * 64 + (size_t)(t >> 2)) * 16384;
    u32 off = (u32)((m & 255) * 64 + ((((t & 3) ^ ((m >> 1) & 3)) << 4)));
    *(uint4*)(Xq + chunk + off) = make_uint4(pk[0], pk[1], pk[2], pk[3]);
  } else {
    // ---- w row: quantize to Wint in {-2..2} ----
    const float alpha = pAlpha[0];
    const int n = b - MDIM;
    const float4* row = W + (size_t)n * 1024;
    float4 v0 = row[t * 4 + 0], v1 = row[t * 4 + 1], v2 = row[t * 4 + 2], v3 = row[t * 4 + 3];
    float vals[16] = {v0.x, v0.y, v0.z, v0.w, v1.x, v1.y, v1.z, v1.w,
                      v2.x, v2.y, v2.z, v2.w, v3.x, v3.y, v3.z, v3.w};
    u32 pk[4];
#pragma unroll
    for (int p = 0; p < 4; ++p) {
      u32 w = 0;
#pragma unroll
      for (int j = 0; j < 4; ++j) {
        int q = (int)quant_wint(vals[p * 4 + j], alpha);   // -2..2 exact
        w |= ((u32)(unsigned char)(signed char)q) << (8 * j);
      }
      pk[p] = w;
    }
    size_t chunk = ((size_t)(n >> 8) * 64 + (size_t)(t >> 2)) * 16384;
    u32 off = (u32)((n & 255) * 64 + ((((t & 3) ^ ((n >> 1) & 3)) << 4)));
    *(uint4*)(Wq + chunk + off) = make_uint4(pk[0], pk[1], pk[2], pk[3]);
  }
}

// ---------- main GEMM: 128x128, BK=64, 256 thr, 3 blocks/CU ----------

#define BM 128
#define BN 128
#define BK 64
#define NKT (KDIM / BK)   // 64

// LDS byte map: Abuf 0..3 @ q*8192; Bbuf 0 @ 32768, Bbuf 1 @ 40960 = 48 KiB
#define LA0 0
#define LA1 8192
#define LA2 16384
#define LA3 24576
#define LB0 32768
#define LB1 40960

__global__ __launch_bounds__(256, 3) void qgemm_kernel(
    const s8* __restrict__ Xq, const s8* __restrict__ Wq,
    const float* __restrict__ scales, const float* __restrict__ pAlpha,
    float* __restrict__ out) {
  __shared__ __align__(16) char sm8[49152];

  const int t256 = threadIdx.x;
  const int lane = t256 & 63;
  const int wave = t256 >> 6;    // 0..3
  const int wm = wave >> 1;      // 0..1
  const int wn = wave & 1;       // 0..1

  // XCD-chunked swizzle: nwg=4096, 8 XCDs, 512 per chunk
  const int bid = blockIdx.x;
  const int nid = (bid & 7) * 512 + (bid >> 3);
  const int m_idx = nid >> 5;    // 128 M-tiles
  const int n_idx = nid & 31;    // 32 N-tiles (consecutive nid share A panel)
  const int m0 = m_idx * BM, n0 = n_idx * BN;

  const float alpha = pAlpha[0];

  v4i acc[4][4] = {};

  // read byte-offset within a 64B row: k-slot (lane>>4), XOR'd by (row>>1)&3
  // (rows below = 16*j + (lane&15) -> (row>>1)&3 == (lane>>1)&3)
  const int koff = (((lane >> 4) ^ ((lane >> 1) & 3)) << 4);

#define AROW(MI) (wm * 64 + (MI)*16 + (lane & 15))
#define BROW(NJ) (wn * 64 + (NJ)*16 + (lane & 15))
#define LDA(AB, MI) (*(const v4i*)(sm8 + (AB) + AROW(MI) * 64 + koff))
#define LDB(BB, NJ) (*(const v4i*)(sm8 + (BB) + BROW(NJ) * 64 + koff))

  // global bases: images are chunked per 256 rows x 64 k (16 KiB); a
  // 128x64 tile is the (m_idx&1) half of chunk (m_idx>>1, KT). KT wraps;
  // junk tail lands only in buffers never read again.
#define GAC(KT) (Xq + ((size_t)(m_idx >> 1) * 64 + (size_t)((KT)&63)) * 16384 + (m_idx & 1) * 8192)
#define GBC(KT) (Wq + ((size_t)(n_idx >> 1) * 64 + (size_t)((KT)&63)) * 16384 + (n_idx & 1) * 8192)

  // stage one 8KB tile: 2 gld16/thread, linear dest
#define STAGE(GBASE, LB) do { \
    const s8* _g = (GBASE) + t256 * 16; \
    gld16(_g, (void*)(sm8 + (LB) + t256 * 16)); \
    gld16(_g + 4096, (void*)(sm8 + (LB) + 4096 + t256 * 16)); \
  } while (0)

#define MFMA8(MI0, MI1, A0, A1) do { \
    acc[MI0][0] = __builtin_amdgcn_mfma_i32_16x16x64_i8(A0, b0, acc[MI0][0], 0, 0, 0); \
    acc[MI0][1] = __builtin_amdgcn_mfma_i32_16x16x64_i8(A0, b1, acc[MI0][1], 0, 0, 0); \
    acc[MI0][2] = __builtin_amdgcn_mfma_i32_16x16x64_i8(A0, b2, acc[MI0][2], 0, 0, 0); \
    acc[MI0][3] = __builtin_amdgcn_mfma_i32_16x16x64_i8(A0, b3, acc[MI0][3], 0, 0, 0); \
    acc[MI1][0] = __builtin_amdgcn_mfma_i32_16x16x64_i8(A1, b0, acc[MI1][0], 0, 0, 0); \
    acc[MI1][1] = __builtin_amdgcn_mfma_i32_16x16x64_i8(A1, b1, acc[MI1][1], 0, 0, 0); \
    acc[MI1][2] = __builtin_amdgcn_mfma_i32_16x16x64_i8(A1, b2, acc[MI1][2], 0, 0, 0); \
    acc[MI1][3] = __builtin_amdgcn_mfma_i32_16x16x64_i8(A1, b3, acc[MI1][3], 0, 0, 0); \
  } while (0)

#define SBAR __builtin_amdgcn_sched_barrier(0)
#define LGKM0 asm volatile("s_waitcnt lgkmcnt(0)" ::: "memory")

#define TILEGATE do { \
    SBAR; \
    asm volatile("s_waitcnt vmcnt(2)" ::: "memory"); \
    __builtin_amdgcn_s_barrier(); \
    SBAR; \
  } while (0)

  // one K-tile: 2 phases. Stages positional: B(t+1), A(t+2) -> tile-end
  // vmcnt(2) leaves exactly A(t+2)'s 2 glds in flight (B(t+1),A(t+1) landed).
#define KTILE(AB, BB, BBN, ASB, TT) do { \
    v4i b0 = LDB(BB, 0), b1 = LDB(BB, 1), b2 = LDB(BB, 2), b3 = LDB(BB, 3); \
    v4i a0 = LDA(AB, 0), a1 = LDA(AB, 1); \
    STAGE(GBC((TT) + 1), BBN); \
    SBAR; LGKM0; SBAR; \
    __builtin_amdgcn_s_setprio(1); \
    MFMA8(0, 1, a0, a1); \
    __builtin_amdgcn_s_setprio(0); \
    SBAR; \
    v4i a2 = LDA(AB, 2), a3 = LDA(AB, 3); \
    STAGE(GAC((TT) + 2), ASB); \
    SBAR; LGKM0; SBAR; \
    __builtin_amdgcn_s_setprio(1); \
    MFMA8(2, 3, a2, a3); \
    __builtin_amdgcn_s_setprio(0); \
    TILEGATE; \
  } while (0)

  // prologue: B(0)->LB0, A(0)->LA0, A(1)->LA1 (6 glds);
  // vmcnt(2) leaves A(1) in flight = steady state.
  STAGE(GBC(0), LB0);
  STAGE(GAC(0), LA0);
  STAGE(GAC(1), LA1);
  asm volatile("s_waitcnt vmcnt(2)" ::: "memory");
  __builtin_amdgcn_s_barrier();
  SBAR;

#pragma unroll 1
  for (int t = 0; t < NKT; t += 4) {
    KTILE(LA0, LB0, LB1, LA2, t);        // reads A(t)  B(t); stages B(t+1)->LB1, A(t+2)->LA2
    KTILE(LA1, LB1, LB0, LA3, t + 1);    // reads A(t+1)B(t+1); stages B(t+2)->LB0, A(t+3)->LA3
    KTILE(LA2, LB0, LB1, LA0, t + 2);    // reads A(t+2)B(t+2); stages B(t+3)->LB1, A(t+4)->LA0
    KTILE(LA3, LB1, LB0, LA1, t + 3);    // reads A(t+3)B(t+3); stages B(t+4)->LB0, A(t+5)->LA1
  }

  // epilogue: out = acc_i32 * scales[row] / (9*alpha)
  const float inv9a = 1.0f / (9.0f * alpha);
#pragma unroll
  for (int mi = 0; mi < 4; ++mi) {
    int rbase = m0 + wm * 64 + mi * 16 + (lane >> 4) * 4;
    float s0 = scales[rbase + 0] * inv9a;
    float s1 = scales[rbase + 1] * inv9a;
    float s2 = scales[rbase + 2] * inv9a;
    float s3 = scales[rbase + 3] * inv9a;
#pragma unroll
    for (int nj = 0; nj < 4; ++nj) {
      int col = n0 + wn * 64 + nj * 16 + (lane & 15);
      out[(size_t)(rbase + 0) * NDIM + col] = (float)acc[mi][nj][0] * s0;
      out[(size_t)(rbase + 1) * NDIM + col] = (float)acc[mi][nj][1] * s1;
      out[(size_t)(rbase + 2) * NDIM + col] = (float)acc[mi][nj][2] * s2;
      out[(size_t)(rbase + 3) * NDIM + col] = (float)acc[mi][nj][3] * s3;
    }
  }
#undef KTILE
#undef TILEGATE
#undef LGKM0
#undef SBAR
#undef MFMA8
#undef STAGE
#undef GAC
#undef GBC
#undef LDA
#undef LDB
#undef AROW
#undef BROW
}

// ---------- fallback (ws too small): fp32 tiled GEMM, quant on the fly ----------

__global__ void fb_gemm_kernel(const float* __restrict__ X, const float* __restrict__ W,
                               const float* __restrict__ pAlpha, float* __restrict__ out) {
  __shared__ float As[64][17];
  __shared__ float Ws[64][17];
  const float alpha = pAlpha[0];
  const float scale = 1.0f / (9.0f * alpha);
  const int bm = blockIdx.x >> 6, bn = blockIdx.x & 63;
  const int t = threadIdx.x;
  const int tx = t & 15, ty = t >> 4;
  float acc[4][4] = {};
  for (int k0 = 0; k0 < KDIM; k0 += 16) {
    int r = t >> 2;
#pragma unroll
    for (int i = 0; i < 4; ++i) {
      int c = (t & 3) * 4 + i;
      As[r][c] = X[(size_t)(bm * 64 + r) * KDIM + k0 + c];
      float w = W[(size_t)(bn * 64 + r) * KDIM + k0 + c];
      Ws[r][c] = quant_wint(w, alpha) * scale;
    }
    __syncthreads();
#pragma unroll
    for (int kk = 0; kk < 16; ++kk)
#pragma unroll
      for (int i = 0; i < 4; ++i)
#pragma unroll
        for (int j = 0; j < 4; ++j)
          acc[i][j] += As[ty * 4 + i][kk] * Ws[tx * 4 + j][kk];
    __syncthreads();
  }
#pragma unroll
  for (int i = 0; i < 4; ++i)
#pragma unroll
    for (int j = 0; j < 4; ++j)
      out[(size_t)(bm * 64 + ty * 4 + i) * NDIM + bn * 64 + tx * 4 + j] = acc[i][j];
}

// ---------- launch ----------

extern "C" void kernel_launch(void* const* d_in, const int* in_sizes, int n_in,
                              void* d_out, int out_size, void* d_ws, size_t ws_size,
                              hipStream_t stream) {
  const float* x = (const float*)d_in[0];       // [16384,4096]
  const float* w = (const float*)d_in[1];       // [4096,4096]
  const float* alpha = (const float*)d_in[2];   // scalar
  float* out = (float*)d_out;

  const size_t XQ_BYTES = (size_t)MDIM * KDIM;              // 67.1 MB
  const size_t WQ_BYTES = (size_t)NDIM * KDIM;              // 16.8 MB
  const size_t SC_BYTES = (size_t)MDIM * 4;                 // 64 KB
  const size_t NEED = XQ_BYTES + WQ_BYTES + SC_BYTES;       // ~84 MB

  if (ws_size >= NEED) {
    s8* Xq = (s8*)d_ws;
    s8* Wq = (s8*)((char*)d_ws + XQ_BYTES);
    float* scales = (float*)((char*)d_ws + XQ_BYTES + WQ_BYTES);
    quant_xw_kernel<<<MDIM + NDIM, 256, 0, stream>>>(
        (const float4*)x, (const float4*)w, alpha, Xq, Wq, scales);
    qgemm_kernel<<<(MDIM / BM) * (NDIM / BN), 256, 0, stream>>>(
        Xq, Wq, scales, alpha, out);
  } else {
    fb_gemm_kernel<<<(MDIM / 64) * (NDIM / 64), 256, 0, stream>>>(x, w, alpha, out);
  }
}

// Round 14
// 412.723 us; speedup vs baseline: 1.0664x; 1.0664x over previous
//
#include <hip/hip_runtime.h>

// QuantizedLinear: out[b,s,o] = sum_k x[b,s,k] * qw[o,k]
// qw = Wint/(9*alpha), Wint in {-2..2}  -> INT8 MFMA GEMM:
//   x quantized per-row to i8 (s_m = rowmax/127), W exact in i8,
//   i32 accumulation exact; epilogue scales by s_m/(9*alpha).
// M=16384, N=4096, K=4096. fp32 in/out.
//
// R14: B bypasses LDS. R8-family is stuck at sum(LDS ~1100, MFMA 1307)
//   cyc/tile; 7 schedule variants +-5%. Cut LDS demand instead: B-frags
//   load global->VGPR (image layout makes each frag a bijective 1KB
//   coalesced read; B is L2/L3-resident; vmem path 25% utilized). LDS
//   traffic 128->80 KB/tile -> below MFMA. A quad-buffered in LDS (64KiB).
//   B regs double-buffered by tile parity. Per-tile vmem issue order
//   [B(t+1)x4, Astage(t+2)x2]; tile gate vmcnt(6) guarantees A(t+1)
//   landed; compiler's counted wait covers B(t+1) at next ph0 without
//   draining A stages.
// Kept: R8 gate discipline (lgkm0+SBAR, R6 spill lesson), 4 clusters/tile,
//   conflict-free (r>>1)&3 image swizzle, XCD-chunked block swizzle,
//   fused prepass, 256x256 tile, 512 thr.

typedef unsigned short u16;
typedef unsigned int u32;
typedef signed char s8;
typedef int v4i __attribute__((ext_vector_type(4)));

#define MDIM 16384
#define NDIM 4096
#define KDIM 4096

// ---------- helpers ----------

__device__ __forceinline__ float quant_wint(float w, float alpha) {
  // nearest of {3.5,4.0,4.5,5.0,5.5} to 4.5*(1+w*alpha); argmin tie -> lower level.
  float tv = 4.5f * (1.0f + w * alpha);
  float u = (tv - 3.5f) * 2.0f;
  float f = ceilf(u - 0.5f);
  f = fminf(fmaxf(f, 0.0f), 4.0f);
  return f - 2.0f;                  // Wint in {-2..2}; scale 1/(9*alpha) in epilogue
}

__device__ __forceinline__ void gld16(const void* g, void* l) {
  __builtin_amdgcn_global_load_lds(
      (const __attribute__((address_space(1))) void*)g,
      (__attribute__((address_space(3))) void*)l, 16, 0, 0);
}

__device__ __forceinline__ int q8(float x, float sinv) {
  float f = rintf(x * sinv);
  f = fminf(fmaxf(f, -127.0f), 127.0f);
  return (int)f;
}

// ---------- fused prepass: X rows then W rows, chunked+swizzled images ----------
// chunk(rowblk256,kblk64) = 16384B; image[r*64 + (c ^ (((r>>1)&3)<<4))]

__global__ __launch_bounds__(256) void quant_xw_kernel(
    const float4* __restrict__ X, const float4* __restrict__ W,
    const float* __restrict__ pAlpha,
    s8* __restrict__ Xq, s8* __restrict__ Wq, float* __restrict__ scales) {
  const int b = blockIdx.x;
  const int t = threadIdx.x;
  if (b < MDIM) {
    // ---- x row: per-row absmax scale -> i8 ----
    const int m = b;
    const float4* row = X + (size_t)m * 1024;
    float4 v0 = row[t * 4 + 0], v1 = row[t * 4 + 1], v2 = row[t * 4 + 2], v3 = row[t * 4 + 3];
    float vals[16] = {v0.x, v0.y, v0.z, v0.w, v1.x, v1.y, v1.z, v1.w,
                      v2.x, v2.y, v2.z, v2.w, v3.x, v3.y, v3.z, v3.w};
    float mx = 0.0f;
#pragma unroll
    for (int j = 0; j < 16; ++j) mx = fmaxf(mx, fabsf(vals[j]));
#pragma unroll
    for (int s = 1; s < 64; s <<= 1) mx = fmaxf(mx, __shfl_xor(mx, s));
    __shared__ float red[4];
    if ((t & 63) == 0) red[t >> 6] = mx;
    __syncthreads();
    float rmax = fmaxf(fmaxf(red[0], red[1]), fmaxf(red[2], red[3]));
    float sinv = rmax > 0.0f ? 127.0f / rmax : 0.0f;
    if (t == 0) scales[m] = rmax * (1.0f / 127.0f);
    u32 pk[4];
#pragma unroll
    for (int p = 0; p < 4; ++p) {
      u32 w = 0;
#pragma unroll
      for (int j = 0; j < 4; ++j)
        w |= ((u32)(unsigned char)(signed char)q8(vals[p * 4 + j], sinv)) << (8 * j);
      pk[p] = w;
    }
    size_t chunk = ((size_t)(m >> 8) * 64 + (size_t)(t >> 2)) * 16384;
    u32 off = (u32)((m & 255) * 64 + ((((t & 3) ^ ((m >> 1) & 3)) << 4)));
    *(uint4*)(Xq + chunk + off) = make_uint4(pk[0], pk[1], pk[2], pk[3]);
  } else {
    // ---- w row: quantize to Wint in {-2..2} ----
    const float alpha = pAlpha[0];
    const int n = b - MDIM;
    const float4* row = W + (size_t)n * 1024;
    float4 v0 = row[t * 4 + 0], v1 = row[t * 4 + 1], v2 = row[t * 4 + 2], v3 = row[t * 4 + 3];
    float vals[16] = {v0.x, v0.y, v0.z, v0.w, v1.x, v1.y, v1.z, v1.w,
                      v2.x, v2.y, v2.z, v2.w, v3.x, v3.y, v3.z, v3.w};
    u32 pk[4];
#pragma unroll
    for (int p = 0; p < 4; ++p) {
      u32 w = 0;
#pragma unroll
      for (int j = 0; j < 4; ++j) {
        int q = (int)quant_wint(vals[p * 4 + j], alpha);   // -2..2 exact
        w |= ((u32)(unsigned char)(signed char)q) << (8 * j);
      }
      pk[p] = w;
    }
    size_t chunk = ((size_t)(n >> 8) * 64 + (size_t)(t >> 2)) * 16384;
    u32 off = (u32)((n & 255) * 64 + ((((t & 3) ^ ((n >> 1) & 3)) << 4)));
    *(uint4*)(Wq + chunk + off) = make_uint4(pk[0], pk[1], pk[2], pk[3]);
  }
}

// ---------- main GEMM: 256x256, BK=64, A in LDS (quad), B global->reg ----------

#define BM 256
#define BN 256
#define BK 64
#define NKT (KDIM / BK)   // 64

// LDS byte map: Abuf 0..3 @ q*16384 = 64 KiB
#define LA0 0
#define LA1 16384
#define LA2 32768
#define LA3 49152

__global__ __launch_bounds__(512, 2) void qgemm_kernel(
    const s8* __restrict__ Xq, const s8* __restrict__ Wq,
    const float* __restrict__ scales, const float* __restrict__ pAlpha,
    float* __restrict__ out) {
  __shared__ __align__(16) char sm8[65536];

  const int t512 = threadIdx.x;
  const int lane = t512 & 63;
  const int wave = t512 >> 6;
  const int wm = wave >> 2;      // 0..1
  const int wn = wave & 3;       // 0..3

  // XCD-chunked swizzle: nwg=1024, 8 XCDs, 128 per chunk
  const int bid = blockIdx.x;
  const int nid = (bid & 7) * 128 + (bid >> 3);
  const int m_idx = nid >> 4;    // 64 M-tiles
  const int n_idx = nid & 15;    // 16 N-tiles (consecutive nid share A panel)
  const int m0 = m_idx * BM, n0 = n_idx * BN;

  const float alpha = pAlpha[0];

  v4i acc[8][4] = {};
  v4i bA0, bA1, bA2, bA3, bB0, bB1, bB2, bB3;   // B frag double-buffer (parity)

  // byte offset within a 64B row: k-slot (lane>>4), XOR'd by (row>>1)&3
  // (rows = 16*j + (lane&15) -> (row>>1)&3 == (lane>>1)&3)
  const int koff = (((lane >> 4) ^ ((lane >> 1) & 3)) << 4);

#define AROW(MI) (wm * 64 + ((MI) >> 2) * 128 + ((MI)&3) * 16 + (lane & 15))
#define BROW(NJ) (wn * 32 + ((NJ) >> 1) * 128 + ((NJ)&1) * 16 + (lane & 15))
#define LDA(AB, MI) (*(const v4i*)(sm8 + (AB) + AROW(MI) * 64 + koff))

  // chunk bases (16 KiB per 256x64 operand tile; KT wraps, junk tail lands
  // only in buffers/regs that are never read again)
#define GAC(KT) (Xq + ((size_t)m_idx * 64 + (size_t)((KT)&63)) * 16384)
  // B frag NJ of k-tile KT, straight from the swizzled image (bijective 1KB)
#define BLD(KT, NJ) \
  (*(const v4i*)(Wq + ((size_t)n_idx * 64 + (size_t)((KT)&63)) * 16384 + BROW(NJ) * 64 + koff))

  // stage one 8KB sweep (S=0/1) of a 16KB A-tile: 1 gld16/thread, linear dest
#define STAGE(GC, S, LB) do { \
    const s8* _g = (GC) + (S)*8192 + wave * 1024 + lane * 16; \
    gld16(_g, (void*)(sm8 + (LB) + (S)*8192 + wave * 1024)); \
  } while (0)

#define MFMA8(MI0, MI1, A0, A1, R0, R1, R2, R3) do { \
    acc[MI0][0] = __builtin_amdgcn_mfma_i32_16x16x64_i8(A0, R0, acc[MI0][0], 0, 0, 0); \
    acc[MI0][1] = __builtin_amdgcn_mfma_i32_16x16x64_i8(A0, R1, acc[MI0][1], 0, 0, 0); \
    acc[MI0][2] = __builtin_amdgcn_mfma_i32_16x16x64_i8(A0, R2, acc[MI0][2], 0, 0, 0); \
    acc[MI0][3] = __builtin_amdgcn_mfma_i32_16x16x64_i8(A0, R3, acc[MI0][3], 0, 0, 0); \
    acc[MI1][0] = __builtin_amdgcn_mfma_i32_16x16x64_i8(A1, R0, acc[MI1][0], 0, 0, 0); \
    acc[MI1][1] = __builtin_amdgcn_mfma_i32_16x16x64_i8(A1, R1, acc[MI1][1], 0, 0, 0); \
    acc[MI1][2] = __builtin_amdgcn_mfma_i32_16x16x64_i8(A1, R2, acc[MI1][2], 0, 0, 0); \
    acc[MI1][3] = __builtin_amdgcn_mfma_i32_16x16x64_i8(A1, R3, acc[MI1][3], 0, 0, 0); \
  } while (0)

#define SBAR __builtin_amdgcn_sched_barrier(0)
#define LGKM0 asm volatile("s_waitcnt lgkmcnt(0)" ::: "memory")

  // tile gate: A(t+1) stages (issued last tile, oldest) must land; this
  // tile's 6 vmem ops (B(t+1)x4 + Astage(t+2)x2) may stay in flight.
#define TILEGATE do { \
    SBAR; \
    asm volatile("s_waitcnt vmcnt(6)" ::: "memory"); \
    __builtin_amdgcn_s_barrier(); \
    SBAR; \
  } while (0)

  // one K-tile: 4 phases. B(t+1) frag loads in ph0/ph1 (before A stages ->
  // compiler's wait at next-tile ph0 is a counted vmcnt that leaves the A
  // stages in flight); A(t+2) stages in ph2/ph3; reads R-set, writes W-set.
#define KTILE(AB, ASB, TT, R0, R1, R2, R3, W0, W1, W2, W3) do { \
    v4i a0 = LDA(AB, 0), a1 = LDA(AB, 1); \
    W0 = BLD((TT) + 1, 0); W1 = BLD((TT) + 1, 1); \
    SBAR; LGKM0; SBAR; \
    __builtin_amdgcn_s_setprio(1); \
    MFMA8(0, 1, a0, a1, R0, R1, R2, R3); \
    __builtin_amdgcn_s_setprio(0); \
    SBAR; \
    v4i a2 = LDA(AB, 2), a3 = LDA(AB, 3); \
    W2 = BLD((TT) + 1, 2); W3 = BLD((TT) + 1, 3); \
    SBAR; LGKM0; SBAR; \
    __builtin_amdgcn_s_setprio(1); \
    MFMA8(2, 3, a2, a3, R0, R1, R2, R3); \
    __builtin_amdgcn_s_setprio(0); \
    SBAR; \
    v4i a4 = LDA(AB, 4), a5 = LDA(AB, 5); \
    STAGE(GAC((TT) + 2), 0, ASB); \
    SBAR; LGKM0; SBAR; \
    __builtin_amdgcn_s_setprio(1); \
    MFMA8(4, 5, a4, a5, R0, R1, R2, R3); \
    __builtin_amdgcn_s_setprio(0); \
    SBAR; \
    v4i a6 = LDA(AB, 6), a7 = LDA(AB, 7); \
    STAGE(GAC((TT) + 2), 1, ASB); \
    SBAR; LGKM0; SBAR; \
    __builtin_amdgcn_s_setprio(1); \
    MFMA8(6, 7, a6, a7, R0, R1, R2, R3); \
    __builtin_amdgcn_s_setprio(0); \
    TILEGATE; \
  } while (0)

  // prologue (order pinned by SBARs to match steady ledger):
  // Astage(0)x2, B(0)x4, Astage(1)x2 -> vmcnt(6) drains A(0) only.
  STAGE(GAC(0), 0, LA0);
  STAGE(GAC(0), 1, LA0);
  SBAR;
  bA0 = BLD(0, 0); bA1 = BLD(0, 1); bA2 = BLD(0, 2); bA3 = BLD(0, 3);
  SBAR;
  STAGE(GAC(1), 0, LA1);
  STAGE(GAC(1), 1, LA1);
  SBAR;
  asm volatile("s_waitcnt vmcnt(6)" ::: "memory");
  __builtin_amdgcn_s_barrier();
  SBAR;

#pragma unroll 1
  for (int t = 0; t < NKT; t += 4) {
    KTILE(LA0, LA2, t,     bA0, bA1, bA2, bA3, bB0, bB1, bB2, bB3);
    KTILE(LA1, LA3, t + 1, bB0, bB1, bB2, bB3, bA0, bA1, bA2, bA3);
    KTILE(LA2, LA0, t + 2, bA0, bA1, bA2, bA3, bB0, bB1, bB2, bB3);
    KTILE(LA3, LA1, t + 3, bB0, bB1, bB2, bB3, bA0, bA1, bA2, bA3);
  }

  // epilogue: out = acc_i32 * scales[row] / (9*alpha)
  const float inv9a = 1.0f / (9.0f * alpha);
#pragma unroll
  for (int mi = 0; mi < 8; ++mi) {
    int rbase = m0 + (mi >> 2) * 128 + wm * 64 + (mi & 3) * 16 + (lane >> 4) * 4;
    float s0 = scales[rbase + 0] * inv9a;
    float s1 = scales[rbase + 1] * inv9a;
    float s2 = scales[rbase + 2] * inv9a;
    float s3 = scales[rbase + 3] * inv9a;
#pragma unroll
    for (int nj = 0; nj < 4; ++nj) {
      int col = n0 + (nj >> 1) * 128 + wn * 32 + (nj & 1) * 16 + (lane & 15);
      out[(size_t)(rbase + 0) * NDIM + col] = (float)acc[mi][nj][0] * s0;
      out[(size_t)(rbase + 1) * NDIM + col] = (float)acc[mi][nj][1] * s1;
      out[(size_t)(rbase + 2) * NDIM + col] = (float)acc[mi][nj][2] * s2;
      out[(size_t)(rbase + 3) * NDIM + col] = (float)acc[mi][nj][3] * s3;
    }
  }
#undef KTILE
#undef TILEGATE
#undef LGKM0
#undef SBAR
#undef MFMA8
#undef STAGE
#undef GAC
#undef BLD
#undef LDA
#undef AROW
#undef BROW
}

// ---------- fallback (ws too small): fp32 tiled GEMM, quant on the fly ----------

__global__ void fb_gemm_kernel(const float* __restrict__ X, const float* __restrict__ W,
                               const float* __restrict__ pAlpha, float* __restrict__ out) {
  __shared__ float As[64][17];
  __shared__ float Ws[64][17];
  const float alpha = pAlpha[0];
  const float scale = 1.0f / (9.0f * alpha);
  const int bm = blockIdx.x >> 6, bn = blockIdx.x & 63;
  const int t = threadIdx.x;
  const int tx = t & 15, ty = t >> 4;
  float acc[4][4] = {};
  for (int k0 = 0; k0 < KDIM; k0 += 16) {
    int r = t >> 2;
#pragma unroll
    for (int i = 0; i < 4; ++i) {
      int c = (t & 3) * 4 + i;
      As[r][c] = X[(size_t)(bm * 64 + r) * KDIM + k0 + c];
      float w = W[(size_t)(bn * 64 + r) * KDIM + k0 + c];
      Ws[r][c] = quant_wint(w, alpha) * scale;
    }
    __syncthreads();
#pragma unroll
    for (int kk = 0; kk < 16; ++kk)
#pragma unroll
      for (int i = 0; i < 4; ++i)
#pragma unroll
        for (int j = 0; j < 4; ++j)
          acc[i][j] += As[ty * 4 + i][kk] * Ws[tx * 4 + j][kk];
    __syncthreads();
  }
#pragma unroll
  for (int i = 0; i < 4; ++i)
#pragma unroll
    for (int j = 0; j < 4; ++j)
      out[(size_t)(bm * 64 + ty * 4 + i) * NDIM + bn * 64 + tx * 4 + j] = acc[i][j];
}

// ---------- launch ----------

extern "C" void kernel_launch(void* const* d_in, const int* in_sizes, int n_in,
                              void* d_out, int out_size, void* d_ws, size_t ws_size,
                              hipStream_t stream) {
  const float* x = (const float*)d_in[0];       // [16384,4096]
  const float* w = (const float*)d_in[1];       // [4096,4096]
  const float* alpha = (const float*)d_in[2];   // scalar
  float* out = (float*)d_out;

  const size_t XQ_BYTES = (size_t)MDIM * KDIM;              // 67.1 MB
  const size_t WQ_BYTES = (size_t)NDIM * KDIM;              // 16.8 MB
  const size_t SC_BYTES = (size_t)MDIM * 4;                 // 64 KB
  const size_t NEED = XQ_BYTES + WQ_BYTES + SC_BYTES;       // ~84 MB

  if (ws_size >= NEED) {
    s8* Xq = (s8*)d_ws;
    s8* Wq = (s8*)((char*)d_ws + XQ_BYTES);
    float* scales = (float*)((char*)d_ws + XQ_BYTES + WQ_BYTES);
    quant_xw_kernel<<<MDIM + NDIM, 256, 0, stream>>>(
        (const float4*)x, (const float4*)w, alpha, Xq, Wq, scales);
    qgemm_kernel<<<(MDIM / BM) * (NDIM / BN), 512, 0, stream>>>(
        Xq, Wq, scales, alpha, out);
  } else {
    fb_gemm_kernel<<<(MDIM / 64) * (NDIM / 64), 256, 0, stream>>>(x, w, alpha, out);
  }
}